// Round 1
// baseline (124.830 us; speedup 1.0000x reference)
//
#include <hip/hip_runtime.h>
#include <hip/hip_bf16.h>

// out[b,n,m] = exp(-(x2[bn] + w2[m] - 2 * (x.w))) + b[m]
// GEMM: 36864 x 512 x 128, bf16 MFMA, fp32 x2/w2/b for accuracy.

typedef __bf16 bf16x8 __attribute__((ext_vector_type(8)));
typedef float f32x4 __attribute__((ext_vector_type(4)));
typedef unsigned short ushort8 __attribute__((ext_vector_type(8)));

#define C_DIM 128
#define M_DIM 512
#define BM 128
#define BN 128
#define LDK 136  // padded LDS k-stride (bf16 elems): 272B row -> conflict-free ds_read_b128

__device__ __forceinline__ unsigned short f2bf_bits(float f) {
  // round-to-nearest-even f32 -> bf16 (no NaN inputs here)
  unsigned int u = __float_as_uint(f);
  u += 0x7fffu + ((u >> 16) & 1u);
  return (unsigned short)(u >> 16);
}

// Pre-pass: transpose w [C][M] f32 -> wT [M][C] bf16, and w2[m] = sum_c w^2 (fp32).
__global__ void prep_w(const float* __restrict__ w,
                       unsigned short* __restrict__ wT,
                       float* __restrict__ w2) {
  const int m = blockIdx.x * 64 + threadIdx.x;  // grid 8 x 64 threads = 512 cols
  float s = 0.f;
#pragma unroll 4
  for (int c = 0; c < C_DIM; ++c) {
    float v = w[c * M_DIM + m];  // coalesced across lanes
    s += v * v;
    wT[m * C_DIM + c] = f2bf_bits(v);  // per-lane sequential bytes; L2 merges
  }
  w2[m] = s;
}

__global__ __launch_bounds__(256)
void gauss_main(const float* __restrict__ x,
                const unsigned short* __restrict__ wT,
                const float* __restrict__ w2,
                const float* __restrict__ b,
                float* __restrict__ out) {
  __shared__ unsigned short As[BM * LDK];  // 34816 B
  __shared__ unsigned short Bs[BN * LDK];  // 34816 B
  __shared__ float x2p[256];
  __shared__ float x2s[BM];
  __shared__ float w2s[BN];
  __shared__ float bs[BN];

  const int t = threadIdx.x;
  const int n0 = blockIdx.x * BN;  // 4 col-blocks
  const int m0 = blockIdx.y * BM;  // 288 row-blocks (288*128 = 36864 exact)

  // --- Stage A: x rows [m0, m0+128) x all 128 k, f32 -> bf16, plus row sumsq (fp32)
  {
    const int r = t >> 1, h = t & 1;  // 2 threads per row, half-row each
    const float* src = x + (size_t)(m0 + r) * C_DIM + h * 64;
    unsigned short* dst = As + r * LDK + h * 64;
    float s = 0.f;
#pragma unroll
    for (int i = 0; i < 8; ++i) {
      float4 f0 = ((const float4*)src)[2 * i];
      float4 f1 = ((const float4*)src)[2 * i + 1];
      s += f0.x * f0.x + f0.y * f0.y + f0.z * f0.z + f0.w * f0.w +
           f1.x * f1.x + f1.y * f1.y + f1.z * f1.z + f1.w * f1.w;
      ushort8 p;
      p[0] = f2bf_bits(f0.x); p[1] = f2bf_bits(f0.y);
      p[2] = f2bf_bits(f0.z); p[3] = f2bf_bits(f0.w);
      p[4] = f2bf_bits(f1.x); p[5] = f2bf_bits(f1.y);
      p[6] = f2bf_bits(f1.z); p[7] = f2bf_bits(f1.w);
      *(ushort8*)(dst + i * 8) = p;
    }
    x2p[t] = s;
  }

  // --- Stage B: wT tile (32 KB contiguous) -> LDS [n][k], uint4 copies
  {
    const uint4* src = (const uint4*)(wT + (size_t)n0 * C_DIM);
#pragma unroll
    for (int i = 0; i < 8; ++i) {
      const int idx = t + i * 256;    // 2048 uint4 total
      uint4 v = src[idx];             // perfectly coalesced
      const int elem = idx * 8;       // bf16 element index within tile
      const int n = elem >> 7, k = elem & 127;
      *(uint4*)(Bs + n * LDK + k) = v;
    }
  }
  if (t < BN) { w2s[t] = w2[n0 + t]; bs[t] = b[n0 + t]; }
  __syncthreads();
  if (t < BM) x2s[t] = x2p[2 * t] + x2p[2 * t + 1];
  __syncthreads();

  // --- MFMA: 4 waves, each 64x64 via 4x4 fragments of 16x16, K = 4 steps of 32
  const int lane = t & 63;
  const int wave = t >> 6;
  const int wr = (wave >> 1) * 64;  // wave row offset
  const int wn = (wave & 1) * 64;   // wave col offset
  const int fm = lane & 15;
  const int q = lane >> 4;

  f32x4 acc[4][4] = {};

#pragma unroll
  for (int ks = 0; ks < 4; ++ks) {
    const int kk = ks * 32 + q * 8;
    bf16x8 af[4], bfr[4];
#pragma unroll
    for (int i = 0; i < 4; ++i)
      af[i] = *(const bf16x8*)(As + (wr + i * 16 + fm) * LDK + kk);
#pragma unroll
    for (int j = 0; j < 4; ++j)
      bfr[j] = *(const bf16x8*)(Bs + (wn + j * 16 + fm) * LDK + kk);
#pragma unroll
    for (int i = 0; i < 4; ++i)
#pragma unroll
      for (int j = 0; j < 4; ++j)
        acc[i][j] = __builtin_amdgcn_mfma_f32_16x16x32_bf16(af[i], bfr[j], acc[i][j], 0, 0, 0);
  }

  // --- Epilogue: d2 = x2 + w2 - 2*xw ; out = exp(-d2) + b
  // C/D layout (verified m89/m91): col = lane&15, row = (lane>>4)*4 + reg
#pragma unroll
  for (int i = 0; i < 4; ++i) {
    const int rbase = wr + i * 16 + q * 4;
#pragma unroll
    for (int j = 0; j < 4; ++j) {
      const int cl = wn + j * 16 + fm;
      const float w2c = w2s[cl];
      const float bc = bs[cl];
      float* po = out + (size_t)(m0 + rbase) * M_DIM + n0 + cl;
#pragma unroll
      for (int rg = 0; rg < 4; ++rg) {
        const float d2 = x2s[rbase + rg] + w2c - 2.0f * acc[i][j][rg];
        po[(size_t)rg * M_DIM] = __expf(-d2) + bc;
      }
    }
  }
}

extern "C" void kernel_launch(void* const* d_in, const int* in_sizes, int n_in,
                              void* d_out, int out_size, void* d_ws, size_t ws_size,
                              hipStream_t stream) {
  const float* x = (const float*)d_in[0];   // [16,48,48,128] = [36864,128]
  const float* w = (const float*)d_in[1];   // [128,512]
  const float* b = (const float*)d_in[2];   // [512]
  float* out = (float*)d_out;               // [36864,512]

  unsigned short* wT = (unsigned short*)d_ws;                          // 512*128*2 = 128 KiB
  float* w2 = (float*)((char*)d_ws + (size_t)M_DIM * C_DIM * 2);       // + 2 KiB

  prep_w<<<dim3(8), dim3(64), 0, stream>>>(w, wT, w2);
  gauss_main<<<dim3(4, 288), dim3(256), 0, stream>>>(x, wT, w2, b, out);
}

// Round 2
// 104.457 us; speedup vs baseline: 1.1950x; 1.1950x over previous
//
#include <hip/hip_runtime.h>
#include <hip/hip_bf16.h>

// out[n,m] = exp(-(x2[n] + w2[m] - 2*(x.wT[m]))) + b[m]
// GEMM 36864 x 512 x 128 (bf16 MFMA) + exp epilogue. Memory-bound:
// ideal HBM traffic = 18.9 MB (x) + 75.5 MB (out) ~ 95 MB -> ~15 us floor.
// exp(-d2) underflows to 0 for this data (d2 ~ 256+-32), so bf16 input
// rounding is invisible at fp32 output precision (round-1 absmax was 0.0).

typedef __bf16 bf16x8 __attribute__((ext_vector_type(8)));
typedef float f32x4 __attribute__((ext_vector_type(4)));
typedef unsigned short ushort4_t __attribute__((ext_vector_type(4)));
typedef unsigned short ushort8_t __attribute__((ext_vector_type(8)));

#define C_DIM 128
#define M_DIM 512
#define BM 64     // rows per block; 36864/64 = 576 blocks (all co-resident)
#define LDK 136   // padded LDS k-stride (bf16): 272 B rows -> conflict-free b128

__device__ __forceinline__ unsigned short f2bf_bits(float f) {
  unsigned int u = __float_as_uint(f);
  u += 0x7fffu + ((u >> 16) & 1u);
  return (unsigned short)(u >> 16);
}

// Transpose w [C][M] f32 -> wT [M][C] bf16 + w2[m] = sum_c w^2.
// LDS-staged: coalesced global loads, coalesced 16B stores.
__global__ __launch_bounds__(256)
void prep_w(const float* __restrict__ w,
            unsigned short* __restrict__ wT,
            float* __restrict__ w2) {
  __shared__ float ws[C_DIM][65];  // +1 pad: transposed reads spread banks
  __shared__ float partial[256];
  const int t = threadIdx.x;
  const int m0 = blockIdx.x * 64;  // 8 blocks x 64 m-columns

  // Load w[:, m0:m0+64]: each instr = 4 rows x 64 consecutive floats (coalesced)
#pragma unroll
  for (int i = 0; i < 32; ++i) {
    const int flat = t + 256 * i;       // 8192 = 128 x 64
    const int c = flat >> 6, mc = flat & 63;
    ws[c][mc] = w[c * M_DIM + m0 + mc];
  }
  __syncthreads();

  // Thread t: output row m = t/4, c-range (t%4)*32 .. +31
  const int m = t >> 2, cq = (t & 3) * 32;
  float s = 0.f;
#pragma unroll
  for (int jj = 0; jj < 4; ++jj) {
    ushort8_t p;
#pragma unroll
    for (int e = 0; e < 8; ++e) {
      const float v = ws[cq + jj * 8 + e][m];
      s += v * v;
      p[e] = f2bf_bits(v);
    }
    // consecutive threads -> consecutive 64B chunks: fully coalesced
    *(ushort8_t*)(wT + (size_t)(m0 + m) * C_DIM + cq + jj * 8) = p;
  }
  partial[t] = s;
  __syncthreads();
  if (t < 64)
    w2[m0 + t] = partial[4 * t] + partial[4 * t + 1] +
                 partial[4 * t + 2] + partial[4 * t + 3];
}

__global__ __launch_bounds__(512)
void gauss_main(const float* __restrict__ x,
                const unsigned short* __restrict__ wT,
                const float* __restrict__ w2,
                const float* __restrict__ b,
                float* __restrict__ out) {
  __shared__ unsigned short As[BM * LDK];    // 17408 B
  __shared__ unsigned short Bs[128 * LDK];   // 34816 B
  __shared__ float x2s[BM];
  __shared__ float w2s[128];
  __shared__ float bs[128];
  // total ~53.5 KB -> 3 blocks/CU, 24 waves/CU

  const int t = threadIdx.x;
  const int lane = t & 63;
  const int wv = t >> 6;          // 8 waves
  const int m0 = blockIdx.x * BM; // 576 blocks

  // --- Stage A: x tile [64][128] f32 -> bf16 LDS, fully coalesced.
  // flat = t + 512*i: lanes 0-31 of a wave = one row's consecutive float4s.
#pragma unroll
  for (int i = 0; i < 4; ++i) {
    const int flat = t + 512 * i;     // 2048 float4 chunks = 64x128 floats
    const int row = flat >> 5;        // 0..63, unique per (wave,half,i)
    const int c4 = (flat & 31) << 2;  // 0,4,...,124
    const float4 f = *(const float4*)(x + (size_t)(m0 + row) * C_DIM + c4);
    float s = f.x * f.x + f.y * f.y + f.z * f.z + f.w * f.w;
    ushort4_t p;
    p[0] = f2bf_bits(f.x); p[1] = f2bf_bits(f.y);
    p[2] = f2bf_bits(f.z); p[3] = f2bf_bits(f.w);
    *(ushort4_t*)(As + row * LDK + c4) = p;
    // fp32 row sum-of-squares: reduce across the 32 lanes sharing this row
    s += __shfl_xor(s, 1);  s += __shfl_xor(s, 2);  s += __shfl_xor(s, 4);
    s += __shfl_xor(s, 8);  s += __shfl_xor(s, 16);
    if ((lane & 31) == 0) x2s[row] = s;
  }

  // --- MFMA geometry: wave wv -> rows [(wv&3)*16, +16), col-half (wv>>2)*64
  const int fm = lane & 15;
  const int q = lane >> 4;
  const int row0 = (wv & 3) * 16;
  const int ch = (wv >> 2) * 64;

#pragma unroll
  for (int nt = 0; nt < 4; ++nt) {
    if (nt) __syncthreads();  // protect Bs/w2s/bs rewrite vs previous epilogue

    // --- Stage B: wT col-tile (32 KB contiguous) -> Bs[n][k], coalesced uint4
    {
      const uint4* src = (const uint4*)(wT + (size_t)nt * 128 * C_DIM);
#pragma unroll
      for (int i = 0; i < 4; ++i) {
        const int idx = t + 512 * i;       // 2048 uint4
        const uint4 v = src[idx];
        const int n = idx >> 4, k = (idx & 15) << 3;
        *(uint4*)(Bs + n * LDK + k) = v;
      }
    }
    if (t < 128) { w2s[t] = w2[nt * 128 + t]; bs[t] = b[nt * 128 + t]; }
    __syncthreads();

    // --- MFMA: 1x4 fragments of 16x16, K = 4 steps of 32
    f32x4 acc[4] = {{0.f, 0.f, 0.f, 0.f}, {0.f, 0.f, 0.f, 0.f},
                    {0.f, 0.f, 0.f, 0.f}, {0.f, 0.f, 0.f, 0.f}};
#pragma unroll
    for (int ks = 0; ks < 4; ++ks) {
      const int kk = ks * 32 + q * 8;
      const bf16x8 af = *(const bf16x8*)(As + (row0 + fm) * LDK + kk);
      bf16x8 bfr[4];
#pragma unroll
      for (int j = 0; j < 4; ++j)
        bfr[j] = *(const bf16x8*)(Bs + (ch + j * 16 + fm) * LDK + kk);
#pragma unroll
      for (int j = 0; j < 4; ++j)
        acc[j] = __builtin_amdgcn_mfma_f32_16x16x32_bf16(af, bfr[j], acc[j], 0, 0, 0);
    }

    // --- Epilogue: C/D layout col=lane&15, row=(lane>>4)*4+reg
    const int rb = row0 + q * 4;
    const float x2v0 = x2s[rb], x2v1 = x2s[rb + 1], x2v2 = x2s[rb + 2], x2v3 = x2s[rb + 3];
#pragma unroll
    for (int j = 0; j < 4; ++j) {
      const int cl = ch + j * 16 + fm;
      const float w2c = w2s[cl];
      const float bc = bs[cl];
      float* po = out + (size_t)(m0 + rb) * M_DIM + nt * 128 + cl;
      po[0]                   = __expf(-(x2v0 + w2c - 2.f * acc[j][0])) + bc;
      po[(size_t)1 * M_DIM]   = __expf(-(x2v1 + w2c - 2.f * acc[j][1])) + bc;
      po[(size_t)2 * M_DIM]   = __expf(-(x2v2 + w2c - 2.f * acc[j][2])) + bc;
      po[(size_t)3 * M_DIM]   = __expf(-(x2v3 + w2c - 2.f * acc[j][3])) + bc;
    }
  }
}

extern "C" void kernel_launch(void* const* d_in, const int* in_sizes, int n_in,
                              void* d_out, int out_size, void* d_ws, size_t ws_size,
                              hipStream_t stream) {
  const float* x = (const float*)d_in[0];   // [36864,128]
  const float* w = (const float*)d_in[1];   // [128,512]
  const float* b = (const float*)d_in[2];   // [512]
  float* out = (float*)d_out;               // [36864,512]

  unsigned short* wT = (unsigned short*)d_ws;                      // 128 KiB
  float* w2 = (float*)((char*)d_ws + (size_t)M_DIM * C_DIM * 2);   // +2 KiB

  prep_w<<<dim3(8), dim3(256), 0, stream>>>(w, wT, w2);
  gauss_main<<<dim3(576), dim3(512), 0, stream>>>(x, wT, w2, b, out);
}